// Round 2
// baseline (92.708 us; speedup 1.0000x reference)
//
#include <hip/hip_runtime.h>

// HierarchicalEmergence: N=2048, M=128, K=8, out = (total, belief, model) fp32.
//
// 2*kl[n,m] = <g_m, d_n> + t_n - K, with
//   per-m:  g = [upper(G) w/ doubled offdiag (36), -2*w (8), c - 2*log|det B| + logdet(Sp) (1)]
//           G = B^T Sp^-1 B, w = B^T Sp^-1 mu_p, c = mu_p^T Sp^-1 mu_p
//   per-n:  d = [upper(C + u u^T) (36), u (8), 1],  C = A^-1 S0 A^-T, u = A^-1 mu0
//           t_n = 2*log|det A| - logdet(S0)
// total = 0.5 * sum_{n,m} W[n,m] * (<g_m,d_n> + t_n - K)
//
// Schedule: 256 blocks x 256 threads. Block b: topdown td=b>>7, n-chunk
// nc=(b>>4)&7 (256 n, one per thread), m-chunk mc=b&15 (8 m).
// Phase 1 (8 lanes of wave 0): g vectors -> LDS. Waves 1-3 overlap their
// n-side factorization with it; single barrier before the dot loop.
// MC=16 replicates the n-side work across CUs that would otherwise idle —
// latency-bound regime, replication is free.

#define N_TOT 2048
#define M_TOT 128
#define NC 8                   // n-chunks
#define MC 16                  // m-chunks
#define MCH (M_TOT / MC)       // 8 m per block
#define NCH (N_TOT / NC)       // 256 n per block (one per thread)
#define NBLOCKS (2 * NC * MC)  // 256
#define GLEN 48                // padded g/d vector length (45 used)

__device__ __forceinline__ void load64(float* dst, const float* __restrict__ src) {
    const float4* p4 = (const float4*)src;
#pragma unroll
    for (int q = 0; q < 16; ++q) {
        float4 v = p4[q];
        dst[4*q+0] = v.x; dst[4*q+1] = v.y; dst[4*q+2] = v.z; dst[4*q+3] = v.w;
    }
}

__global__ __launch_bounds__(256, 1)
void he_main(const float* __restrict__ W,
             const float* __restrict__ mu_p,  const float* __restrict__ sig_p,
             const float* __restrict__ mu_qp, const float* __restrict__ sig_qp,
             const float* __restrict__ om_c,  const float* __restrict__ om_p,
             const float* __restrict__ mu_r,  const float* __restrict__ sig_r,
             const float* __restrict__ mu_sp, const float* __restrict__ sig_sp,
             const float* __restrict__ om_mc, const float* __restrict__ om_mp,
             double* __restrict__ partials)
{
    __shared__ float g_l[MCH][GLEN];
    __shared__ double red[4];

    const int b   = blockIdx.x;
    const int td  = b >> 7;        // 0 = belief, 1 = model
    const int nc  = (b >> 4) & 7;
    const int mc  = b & 15;
    const int tid = threadIdx.x;

    const float* muC = td ? mu_r   : mu_p;
    const float* SC  = td ? sig_r  : sig_p;
    const float* OC  = td ? om_mc  : om_c;
    const float* muP = td ? mu_sp  : mu_qp;
    const float* SP  = td ? sig_sp : sig_qp;
    const float* OP  = td ? om_mp  : om_p;

    // ---------------- phase 1: per-m g vectors (lanes 0..7 of wave 0) -------
    if (tid < MCH) {
        const int m = mc * MCH + tid;

        // Cholesky of Sp (in place, lower)
        float L[64];
        load64(L, SP + m * 64);
        float invd[8];
        float lsp = 0.f;
#pragma unroll
        for (int i = 0; i < 8; ++i) {
#pragma unroll
            for (int j = 0; j <= i; ++j) {
                float s = L[i*8+j];
#pragma unroll
                for (int k = 0; k < j; ++k) s -= L[i*8+k] * L[j*8+k];
                if (j == i) {
                    float d = sqrtf(s);
                    L[i*8+i] = d; invd[i] = 1.0f / d; lsp += logf(d);
                } else {
                    L[i*8+j] = s * invd[j];
                }
            }
        }
        lsp *= 2.0f;

        // z = L^-1 mu_par ; c = z.z
        float z[8]; float cq = 0.f;
#pragma unroll
        for (int i = 0; i < 8; ++i) {
            float s = muP[m*8 + i];
#pragma unroll
            for (int k = 0; k < i; ++k) s -= L[i*8+k] * z[k];
            z[i] = s * invd[i];
            cq += z[i] * z[i];
        }

        // Y = L^-1 B   (B = Omega_parent)
        float B[64];
        load64(B, OP + m * 64);
        float Y[64];
#pragma unroll
        for (int i = 0; i < 8; ++i) {
#pragma unroll
            for (int c8 = 0; c8 < 8; ++c8) {
                float s = B[i*8+c8];
#pragma unroll
                for (int k = 0; k < i; ++k) s -= L[i*8+k] * Y[k*8+c8];
                Y[i*8+c8] = s * invd[i];
            }
        }

        // G = Y^T Y (upper, doubled off-diag) and w = Y^T z
        int t = 0;
#pragma unroll
        for (int a = 0; a < 8; ++a) {
#pragma unroll
            for (int bb = a; bb < 8; ++bb) {
                float s = 0.f;
#pragma unroll
                for (int i = 0; i < 8; ++i) s += Y[i*8+a] * Y[i*8+bb];
                g_l[tid][t++] = (bb == a) ? s : 2.0f * s;
            }
        }
#pragma unroll
        for (int a = 0; a < 8; ++a) {
            float s = 0.f;
#pragma unroll
            for (int i = 0; i < 8; ++i) s += Y[i*8+a] * z[i];
            g_l[tid][36 + a] = -2.0f * s;
        }

        // log|det B| via no-pivot LU (B = I + 0.1*noise: safely diagonal-ish)
        float lb = 0.f;
#pragma unroll
        for (int k = 0; k < 8; ++k) {
            lb += logf(fabsf(B[k*8+k]));
            float r = 1.0f / B[k*8+k];
#pragma unroll
            for (int i = k + 1; i < 8; ++i) {
                float f = B[i*8+k] * r;
#pragma unroll
                for (int j = k + 1; j < 8; ++j) B[i*8+j] -= f * B[k*8+j];
            }
        }
        g_l[tid][44] = cq - 2.0f * lb + lsp;
        g_l[tid][45] = 0.f; g_l[tid][46] = 0.f; g_l[tid][47] = 0.f; // pad
    }

    // ---------------- phase 2: one n per thread (overlaps phase 1) ----------
    const int n = nc * NCH + tid;

    // W chunk (8 floats) + row-chunk sum
    float wreg[MCH];
    float wsum = 0.f;
    {
        const float4* wrow = (const float4*)(W + n * M_TOT + mc * MCH);
#pragma unroll
        for (int q = 0; q < MCH / 4; ++q) {
            float4 v = wrow[q];
            wreg[4*q+0] = v.x; wreg[4*q+1] = v.y; wreg[4*q+2] = v.z; wreg[4*q+3] = v.w;
            wsum += v.x + v.y + v.z + v.w;
        }
    }

    // LU of A = Omega_child (no pivot): unit-L below diag, U on/above.
    float Um[64];
    load64(Um, OC + n * 64);
    float la = 0.f; float invu[8];
#pragma unroll
    for (int k = 0; k < 8; ++k) {
        la += logf(fabsf(Um[k*8+k]));
        float r = 1.0f / Um[k*8+k];
        invu[k] = r;
#pragma unroll
        for (int i = k + 1; i < 8; ++i) {
            float f = Um[i*8+k] * r;
            Um[i*8+k] = f;  // store L factor
#pragma unroll
            for (int j = k + 1; j < 8; ++j) Um[i*8+j] -= f * Um[k*8+j];
        }
    }

    // Cholesky of S0 (lower) -> logdet
    float Ls[64];
    load64(Ls, SC + n * 64);
    float invd2[8];
    float ls0 = 0.f;
#pragma unroll
    for (int i = 0; i < 8; ++i) {
#pragma unroll
        for (int j = 0; j <= i; ++j) {
            float s = Ls[i*8+j];
#pragma unroll
            for (int k = 0; k < j; ++k) s -= Ls[i*8+k] * Ls[j*8+k];
            if (j == i) {
                float d = sqrtf(s);
                Ls[i*8+i] = d; invd2[i] = 1.0f / d; ls0 += logf(d);
            } else {
                Ls[i*8+j] = s * invd2[j];
            }
        }
    }
    ls0 *= 2.0f;

    // Mt = A^-1 * Ls via LU solves per column (no explicit inverse).
    // Ls is lower-tri => forward-solve y is 0 above row j.
    float Mt[64];
#pragma unroll
    for (int j = 0; j < 8; ++j) {
        float y[8];
#pragma unroll
        for (int i = 0; i < 8; ++i) {
            if (i < j) { y[i] = 0.f; }
            else {
                float s = Ls[i*8+j];
#pragma unroll
                for (int k = j; k < i; ++k) s -= Um[i*8+k] * y[k];
                y[i] = s;
            }
        }
#pragma unroll
        for (int i = 7; i >= 0; --i) {
            float s = y[i];
#pragma unroll
            for (int k = i + 1; k < 8; ++k) s -= Um[i*8+k] * Mt[k*8+j];
            Mt[i*8+j] = s * invu[i];
        }
    }

    // u = A^-1 mu0 via LU solves
    float mu0[8];
    {
        const float4* p4 = (const float4*)(muC + n * 8);
        float4 v0 = p4[0], v1 = p4[1];
        mu0[0]=v0.x; mu0[1]=v0.y; mu0[2]=v0.z; mu0[3]=v0.w;
        mu0[4]=v1.x; mu0[5]=v1.y; mu0[6]=v1.z; mu0[7]=v1.w;
    }
    float u[8];
    {
        float y[8];
#pragma unroll
        for (int i = 0; i < 8; ++i) {
            float s = mu0[i];
#pragma unroll
            for (int k = 0; k < i; ++k) s -= Um[i*8+k] * y[k];
            y[i] = s;
        }
#pragma unroll
        for (int i = 7; i >= 0; --i) {
            float s = y[i];
#pragma unroll
            for (int k = i + 1; k < 8; ++k) s -= Um[i*8+k] * u[k];
            u[i] = s * invu[i];
        }
    }

    // d vector: upper(Mt Mt^T + u u^T) (36), u (8), 1, pad
    float dv[GLEN];
    {
        int t = 0;
#pragma unroll
        for (int a = 0; a < 8; ++a) {
#pragma unroll
            for (int bb = a; bb < 8; ++bb) {
                float s = u[a] * u[bb];
#pragma unroll
                for (int k = 0; k < 8; ++k) s += Mt[a*8+k] * Mt[bb*8+k];
                dv[t++] = s;
            }
        }
    }
#pragma unroll
    for (int a = 0; a < 8; ++a) dv[36 + a] = u[a];
    dv[44] = 1.0f; dv[45] = 0.f; dv[46] = 0.f; dv[47] = 0.f;

    const float tn = 2.0f * la - ls0;

    __syncthreads();  // g_l ready (phase 1 ran on wave 0 in parallel)

    // weighted bilinear reduction over this block's m-chunk (LDS broadcast)
    float acc = 0.f;
#pragma unroll
    for (int j = 0; j < MCH; ++j) {
        const float4* gr = (const float4*)&g_l[j][0];
        float dot = 0.f;
#pragma unroll
        for (int q = 0; q < GLEN / 4; ++q) {
            float4 gv = gr[q];
            dot += gv.x * dv[4*q+0] + gv.y * dv[4*q+1]
                 + gv.z * dv[4*q+2] + gv.w * dv[4*q+3];
        }
        acc += wreg[j] * dot;
    }

    double part = 0.5 * ((double)acc + (double)wsum * ((double)tn - 8.0));

    // block reduction (4 waves) in double
#pragma unroll
    for (int off = 32; off > 0; off >>= 1) part += __shfl_down(part, off, 64);
    if ((tid & 63) == 0) red[tid >> 6] = part;
    __syncthreads();
    if (tid == 0) partials[b] = red[0] + red[1] + red[2] + red[3];
}

__global__ void he_finalize(const double* __restrict__ partials, float* __restrict__ out)
{
    __shared__ double sh[4];
    const int tid = threadIdx.x;        // 256 threads, 4 waves
    double v = partials[tid];           // blocks 0..127 belief, 128..255 model
#pragma unroll
    for (int off = 32; off > 0; off >>= 1) v += __shfl_down(v, off, 64);
    if ((tid & 63) == 0) sh[tid >> 6] = v;
    __syncthreads();
    if (tid == 0) {
        double belief = sh[0] + sh[1];
        double model  = sh[2] + sh[3];
        out[0] = (float)(belief + model);  // LAMBDA_BELIEF = LAMBDA_MODEL = 1
        out[1] = (float)belief;
        out[2] = (float)model;
    }
}

extern "C" void kernel_launch(void* const* d_in, const int* in_sizes, int n_in,
                              void* d_out, int out_size, void* d_ws, size_t ws_size,
                              hipStream_t stream)
{
    const float* W      = (const float*)d_in[0];
    const float* mu_p   = (const float*)d_in[1];
    const float* sig_p  = (const float*)d_in[2];
    const float* mu_qp  = (const float*)d_in[3];
    const float* sig_qp = (const float*)d_in[4];
    const float* om_c   = (const float*)d_in[5];
    const float* om_p   = (const float*)d_in[6];
    const float* mu_r   = (const float*)d_in[7];
    const float* sig_r  = (const float*)d_in[8];
    const float* mu_sp  = (const float*)d_in[9];
    const float* sig_sp = (const float*)d_in[10];
    const float* om_mc  = (const float*)d_in[11];
    const float* om_mp  = (const float*)d_in[12];

    double* partials = (double*)d_ws;   // 256 doubles = 2 KB of scratch

    he_main<<<NBLOCKS, 256, 0, stream>>>(W, mu_p, sig_p, mu_qp, sig_qp, om_c, om_p,
                                         mu_r, sig_r, mu_sp, sig_sp, om_mc, om_mp,
                                         partials);
    he_finalize<<<1, 256, 0, stream>>>(partials, (float*)d_out);
}